// Round 3
// baseline (546.165 us; speedup 1.0000x reference)
//
#include <hip/hip_runtime.h>

// Problem constants (from reference) — ALL TENSORS ARE FLOAT32.
#define NPP   64
#define NRR   8
#define NKK   500
#define HDIM  256
#define NHEAD 8
#define VDIM  8
#define HD    32
#define BTOT  512   // NPP*NRR

__device__ __forceinline__ float sigf(float x) { return 1.f / (1.f + expf(-x)); }

// ---------------------------------------------------------------------------
// Kernel 1: LSTM cell.  gates = q@W_ih^T + b_ih + s1@W_hh^T + b_hh
// grid 128 x 256thr, each block does RB1=4 batch rows (weights reused 4x).
// ---------------------------------------------------------------------------
#define RB1 4
__global__ __launch_bounds__(256) void k_lstm(
    const float* __restrict__ query, const float* __restrict__ state1,
    const float* __restrict__ state2,
    const float* __restrict__ W_ih, const float* __restrict__ W_hh,
    const float* __restrict__ b_ih, const float* __restrict__ b_hh,
    float* __restrict__ out_h, float* __restrict__ out_c)
{
  __shared__ float qs[RB1][HDIM];
  __shared__ float ss[RB1][HDIM];
  const int t  = threadIdx.x;
  const int b0 = blockIdx.x * RB1;

  for (int idx = t; idx < RB1 * HDIM; idx += 256) {
    int r = idx >> 8, j = idx & 255;
    qs[r][j] = query [(size_t)(b0 + r) * HDIM + j];
    ss[r][j] = state1[(size_t)(b0 + r) * HDIM + j];
  }
  __syncthreads();

  float g[4][RB1];
  for (int part = 0; part < 4; ++part) {
    const int row = part * HDIM + t;
    const float bias = b_ih[row] + b_hh[row];
    float a[RB1];
#pragma unroll
    for (int r = 0; r < RB1; ++r) a[r] = bias;
    const float4* wi4 = reinterpret_cast<const float4*>(W_ih + (size_t)row * HDIM);
    const float4* wh4 = reinterpret_cast<const float4*>(W_hh + (size_t)row * HDIM);
    for (int j4 = 0; j4 < HDIM / 4; ++j4) {
      const float4 wi = wi4[j4], wh = wh4[j4];
      const int j = j4 * 4;
#pragma unroll
      for (int r = 0; r < RB1; ++r) {
        a[r] += wi.x * qs[r][j]     + wi.y * qs[r][j + 1]
              + wi.z * qs[r][j + 2] + wi.w * qs[r][j + 3]
              + wh.x * ss[r][j]     + wh.y * ss[r][j + 1]
              + wh.z * ss[r][j + 2] + wh.w * ss[r][j + 3];
      }
    }
#pragma unroll
    for (int r = 0; r < RB1; ++r) g[part][r] = a[r];
  }

#pragma unroll
  for (int r = 0; r < RB1; ++r) {
    const float iv = sigf(g[0][r]);
    const float fv = sigf(g[1][r]);
    const float gv = tanhf(g[2][r]);
    const float ov = sigf(g[3][r]);
    const size_t off = (size_t)(b0 + r) * HDIM + t;
    const float c = fv * state2[off] + iv * gv;
    const float h = ov * tanhf(c);
    out_h[off] = h;
    out_c[off] = c;
  }
}

// ---------------------------------------------------------------------------
// Kernel 2: fully fused per-(p,r) block: 8-head glimpse attention + output
// projection + additive logits + choose.  All intermediates in LDS; zero
// global workspace.  Reads h from out_h (fp32).  512 blocks x 256 threads.
// ---------------------------------------------------------------------------
__global__ __launch_bounds__(256) void k_fused(
    const float* __restrict__ X, const float* __restrict__ Kt,
    const float* __restrict__ Vt, const float* __restrict__ varfeat,
    const void* __restrict__ maskp,
    const float* __restrict__ nn_Q, const float* __restrict__ nn_O,
    const float* __restrict__ nn_A, const float* __restrict__ nn_B,
    const float* __restrict__ nn_W,
    const float* __restrict__ out_h, float* __restrict__ out_p)
{
  const int p    = blockIdx.x >> 3;
  const int r    = blockIdx.x & 7;
  const int t    = threadIdx.x;
  const int wave = t >> 6;
  const int lane = t & 63;

  __shared__ float hs[HDIM];          // h row (f32)           1 KB
  __shared__ float Qs[NHEAD][HD];     // projected queries     1 KB
  __shared__ float Sb[NHEAD][NKK];    // scores / probs       16 KB
  __shared__ float xs[HDIM];          // attention output      1 KB
  __shared__ float qs[HDIM];          // qm row + nn_B         1 KB
  __shared__ float As[HDIM][VDIM];    // nn_A transposed       8 KB
  __shared__ float Ws[HDIM];          // nn_W                  1 KB
  __shared__ float ls[NKK];           // logits                2 KB
  __shared__ int   mask_any;

  const unsigned char* mb = (const unsigned char*)maskp;

  // ---- mask dtype probe: int32 mask (values 0/1) has all-zero odd bytes;
  //      a 10%-dense 1-byte bool mask has ~200 nonzero odd bytes in 4 KB.
  if (t == 0) mask_any = 0;
  __syncthreads();
  {
    int any = 0;
    for (int j = t; j < 2048; j += 256) any |= mb[2 * j + 1];
    if (any) atomicOr(&mask_any, 1);
  }

  // ---- preload small weights into LDS ----
  for (int idx = t; idx < VDIM * HDIM; idx += 256) {
    const int v = idx >> 8, h = idx & 255;           // nn_A is [v][h]
    As[h][v] = nn_A[idx];
  }
  Ws[t] = nn_W[t];
  hs[t] = out_h[(size_t)(p * NRR + r) * HDIM + t];
  __syncthreads();

  const bool mask_is_byte = (mask_any != 0);
  const int* mi = (const int*)maskp;
  const size_t mrow = (size_t)(p * NRR + r) * NKK;

  // ---- Q projection: thread -> (head a, dim d) ----
  {
    const int a = t >> 5, d = t & 31;
    const float* nq = nn_Q + (size_t)a * HDIM * HD + d;
    float acc = 0.f;
    for (int h = 0; h < HDIM; ++h) acc += hs[h] * nq[(size_t)h * HD];
    Qs[a][d] = acc * 0.17677669529663687f;   // 1/sqrt(32)
  }
  __syncthreads();

  // ---- scores for all heads: thread <-> k ----
  for (int k = t; k < NKK; k += 256) {
    const bool mk = mask_is_byte ? (mb[mrow + k] != 0) : (mi[mrow + k] != 0);
#pragma unroll
    for (int a = 0; a < NHEAD; ++a) {
      const float4* kr4 = reinterpret_cast<const float4*>(
          Kt + (((size_t)a * NPP + p) * NKK + k) * HD);
      float s = 0.f;
#pragma unroll
      for (int d4 = 0; d4 < HD / 4; ++d4) {
        const float4 u = kr4[d4];
        s += Qs[a][4 * d4 + 0] * u.x + Qs[a][4 * d4 + 1] * u.y
           + Qs[a][4 * d4 + 2] * u.z + Qs[a][4 * d4 + 3] * u.w;
      }
      Sb[a][k] = mk ? -INFINITY : s;
    }
  }
  __syncthreads();

  // ---- softmax per head: wave w handles heads 2w, 2w+1 ----
  for (int aa = 0; aa < 2; ++aa) {
    const int a = wave * 2 + aa;
    float m = -INFINITY;
    for (int k = lane; k < NKK; k += 64) m = fmaxf(m, Sb[a][k]);
#pragma unroll
    for (int off = 32; off > 0; off >>= 1) m = fmaxf(m, __shfl_xor(m, off, 64));
    float ssum = 0.f;
    for (int k = lane; k < NKK; k += 64) {
      float e = expf(Sb[a][k] - m);
      Sb[a][k] = e;
      ssum += e;
    }
#pragma unroll
    for (int off = 32; off > 0; off >>= 1) ssum += __shfl_xor(ssum, off, 64);
    const float inv = 1.f / ssum;
    for (int k = lane; k < NKK; k += 64) Sb[a][k] *= inv;
  }
  __syncthreads();

  // ---- PV: thread -> (head a, dim d) ----
  {
    const int a = t >> 5, d = t & 31;
    const float* vb = Vt + ((size_t)a * NPP + p) * NKK * HD + d;
    float acc = 0.f;
    for (int k = 0; k < NKK; ++k) acc += Sb[a][k] * vb[(size_t)k * HD];
    xs[a * HD + d] = acc;                    // [NP,NR,heads,HD] flatten order
  }
  __syncthreads();

  // ---- qm = xs @ nn_O (+ nn_B folded in): thread = output dim ----
  {
    float acc = 0.f;
    for (int i = 0; i < HDIM; ++i) acc += xs[i] * nn_O[(size_t)i * HDIM + t];
    qs[t] = acc + nn_B[t];
  }
  __syncthreads();

  // ---- additive logits: thread <-> k ----
  for (int k = t; k < NKK; k += 256) {
    float vfv[VDIM];
#pragma unroll
    for (int v = 0; v < VDIM; ++v)
      vfv[v] = varfeat[((size_t)p * VDIM + v) * NKK + k];
    const float4* xp4 = reinterpret_cast<const float4*>(
        X + ((size_t)p * NKK + k) * HDIM);
    float acc = 0.f;
    for (int h4 = 0; h4 < HDIM / 4; ++h4) {
      const float4 ux = xp4[h4];
      const float xv[4] = {ux.x, ux.y, ux.z, ux.w};
#pragma unroll
      for (int j = 0; j < 4; ++j) {
        const int h = 4 * h4 + j;
        float base = xv[j] + qs[h];
        const float4 a0 = *reinterpret_cast<const float4*>(&As[h][0]);
        const float4 a1 = *reinterpret_cast<const float4*>(&As[h][4]);
        base += vfv[0] * a0.x + vfv[1] * a0.y + vfv[2] * a0.z + vfv[3] * a0.w
              + vfv[4] * a1.x + vfv[5] * a1.y + vfv[6] * a1.z + vfv[7] * a1.w;
        acc += tanhf(base) * Ws[h];
      }
    }
    ls[k] = acc;
  }
  __syncthreads();

  // ---- choose: l = mask ? -inf : tanh(logit)*10 ; p = -log(sum exp(l-max)) ----
  for (int k = t; k < NKK; k += 256) {
    const bool mk = mask_is_byte ? (mb[mrow + k] != 0) : (mi[mrow + k] != 0);
    ls[k] = mk ? -INFINITY : tanhf(ls[k]) * 10.0f;
  }
  __syncthreads();
  if (wave == 0) {
    float m = -INFINITY;
    for (int k = lane; k < NKK; k += 64) m = fmaxf(m, ls[k]);
#pragma unroll
    for (int off = 32; off > 0; off >>= 1) m = fmaxf(m, __shfl_xor(m, off, 64));
    float s = 0.f;
    for (int k = lane; k < NKK; k += 64) s += expf(ls[k] - m);
#pragma unroll
    for (int off = 32; off > 0; off >>= 1) s += __shfl_xor(s, off, 64);
    if (lane == 0) out_p[p * NRR + r] = -logf(s);   // logp at argmax = max - lse
  }
}

// ---------------------------------------------------------------------------
extern "C" void kernel_launch(void* const* d_in, const int* in_sizes, int n_in,
                              void* d_out, int out_size, void* d_ws, size_t ws_size,
                              hipStream_t stream)
{
  const float* X       = (const float*)d_in[0];
  const float* Kt      = (const float*)d_in[1];
  const float* Vt      = (const float*)d_in[2];
  const float* query   = (const float*)d_in[3];
  const float* state1  = (const float*)d_in[4];
  const float* state2  = (const float*)d_in[5];
  const float* varfeat = (const float*)d_in[6];
  const void*  maskp   = d_in[7];
  const float* nn_Q    = (const float*)d_in[8];
  const float* nn_O    = (const float*)d_in[9];
  const float* nn_A    = (const float*)d_in[10];
  const float* nn_B    = (const float*)d_in[11];
  const float* nn_W    = (const float*)d_in[12];
  const float* W_ih    = (const float*)d_in[13];
  const float* W_hh    = (const float*)d_in[14];
  const float* b_ih    = (const float*)d_in[15];
  const float* b_hh    = (const float*)d_in[16];

  float* out   = (float*)d_out;
  float* out_h = out;                              // [512,256]
  float* out_c = out + (size_t)BTOT * HDIM;        // [512,256]
  float* out_p = out + (size_t)2 * BTOT * HDIM;    // [512]

  (void)d_ws; (void)ws_size;   // zero-workspace design

  hipLaunchKernelGGL(k_lstm, dim3(BTOT / RB1), dim3(256), 0, stream,
                     query, state1, state2, W_ih, W_hh, b_ih, b_hh,
                     out_h, out_c);
  hipLaunchKernelGGL(k_fused, dim3(NPP * NRR), dim3(256), 0, stream,
                     X, Kt, Vt, varfeat, maskp,
                     nn_Q, nn_O, nn_A, nn_B, nn_W,
                     out_h, out_p);
}

// Round 4
// 328.359 us; speedup vs baseline: 1.6633x; 1.6633x over previous
//
#include <hip/hip_runtime.h>

// Problem constants (from reference) — ALL TENSORS ARE FLOAT32.
#define NPP   64
#define NRR   8
#define NKK   500
#define HDIM  256
#define NHEAD 8
#define VDIM  8
#define HD    32
#define BTOT  512   // NPP*NRR

__device__ __forceinline__ float sigf(float x) { return 1.f / (1.f + expf(-x)); }

// ===========================================================================
// Kernel 1: LSTM cell as a tiled GEMM with fused gate epilogue.
// gates[512,1024] = [query|state1] @ [W_ih|W_hh]^T  (K = 512)
// Block tile: 32 gate rows (4 parts x 8 h) x 64 batch.  Grid 32 x 8 = 256.
// ===========================================================================
__global__ __launch_bounds__(256) void k_lstm2(
    const float* __restrict__ query, const float* __restrict__ state1,
    const float* __restrict__ state2,
    const float* __restrict__ W_ih, const float* __restrict__ W_hh,
    const float* __restrict__ b_ih, const float* __restrict__ b_hh,
    float* __restrict__ out_h, float* __restrict__ out_c)
{
  __shared__ float Wt[32][34];   // [kk][row_local]   (transposed W tile)
  __shared__ float At[32][68];   // [kk][batch_local] (transposed act tile)
  __shared__ float gt[32][65];   // [row_local][batch_local] epilogue tile

  const int t  = threadIdx.x;
  const int hb = blockIdx.x >> 3;   // 0..31  (8 h per tile)
  const int bb = blockIdx.x & 7;    // 0..7   (64 batch per tile)

  const int trg = t >> 4;           // 0..15 -> rows 2*trg, 2*trg+1
  const int tb  = t & 15;           // 0..15 -> batch 4*tb .. +3

  float acc[2][4];
#pragma unroll
  for (int i = 0; i < 2; ++i)
#pragma unroll
    for (int j = 0; j < 4; ++j) acc[i][j] = 0.f;

  // W-load mapping: row_l = t>>3 (0..31), kc = t&7 (float4 col)
  const int wrow_l = t >> 3, wkc = t & 7;
  const int wpart = wrow_l >> 3, whh = wrow_l & 7;
  const int wgrow = wpart * HDIM + hb * 8 + whh;        // global gate row
  // A-load mapping: b_l = t>>2 (0..63), kc2 = t&3 (two float4s)
  const int ab_l = t >> 2, akc = t & 3;
  const int agrow = bb * 64 + ab_l;                     // global batch row

  for (int k0 = 0; k0 < 512; k0 += 32) {
    __syncthreads();
    {
      const float* wsrc = (k0 < 256) ? (W_ih + (size_t)wgrow * HDIM + k0)
                                     : (W_hh + (size_t)wgrow * HDIM + (k0 - 256));
      const float4 wv = *reinterpret_cast<const float4*>(wsrc + wkc * 4);
      Wt[wkc * 4 + 0][wrow_l] = wv.x;
      Wt[wkc * 4 + 1][wrow_l] = wv.y;
      Wt[wkc * 4 + 2][wrow_l] = wv.z;
      Wt[wkc * 4 + 3][wrow_l] = wv.w;

      const float* asrc = (k0 < 256) ? (query  + (size_t)agrow * HDIM + k0)
                                     : (state1 + (size_t)agrow * HDIM + (k0 - 256));
      const float4 a0 = *reinterpret_cast<const float4*>(asrc + akc * 8);
      const float4 a1 = *reinterpret_cast<const float4*>(asrc + akc * 8 + 4);
      At[akc * 8 + 0][ab_l] = a0.x; At[akc * 8 + 1][ab_l] = a0.y;
      At[akc * 8 + 2][ab_l] = a0.z; At[akc * 8 + 3][ab_l] = a0.w;
      At[akc * 8 + 4][ab_l] = a1.x; At[akc * 8 + 5][ab_l] = a1.y;
      At[akc * 8 + 6][ab_l] = a1.z; At[akc * 8 + 7][ab_l] = a1.w;
    }
    __syncthreads();

#pragma unroll 8
    for (int kk = 0; kk < 32; ++kk) {
      const float2 wv = *reinterpret_cast<const float2*>(&Wt[kk][2 * trg]);
      const float4 av = *reinterpret_cast<const float4*>(&At[kk][4 * tb]);
      acc[0][0] += wv.x * av.x; acc[0][1] += wv.x * av.y;
      acc[0][2] += wv.x * av.z; acc[0][3] += wv.x * av.w;
      acc[1][0] += wv.y * av.x; acc[1][1] += wv.y * av.y;
      acc[1][2] += wv.y * av.z; acc[1][3] += wv.y * av.w;
    }
  }

  // park accumulators in LDS for the cross-part epilogue
#pragma unroll
  for (int i = 0; i < 2; ++i)
#pragma unroll
    for (int j = 0; j < 4; ++j) gt[2 * trg + i][4 * tb + j] = acc[i][j];
  __syncthreads();

  // epilogue: 512 (h,b) cells, 2 per thread; lanes contiguous in h (32B runs)
#pragma unroll
  for (int rep = 0; rep < 2; ++rep) {
    const int cell = rep * 256 + t;
    const int h = cell & 7, b = cell >> 3;
    const int gh = hb * 8 + h;                 // global hidden index
    const int gb = bb * 64 + b;                // global batch index
    const float bi = b_ih[0 * HDIM + gh] + b_hh[0 * HDIM + gh];
    const float bf = b_ih[1 * HDIM + gh] + b_hh[1 * HDIM + gh];
    const float bg = b_ih[2 * HDIM + gh] + b_hh[2 * HDIM + gh];
    const float bo = b_ih[3 * HDIM + gh] + b_hh[3 * HDIM + gh];
    const float iv = sigf (gt[ 0 + h][b] + bi);
    const float fv = sigf (gt[ 8 + h][b] + bf);
    const float gv = tanhf(gt[16 + h][b] + bg);
    const float ov = sigf (gt[24 + h][b] + bo);
    const size_t off = (size_t)gb * HDIM + gh;
    const float c = fv * state2[off] + iv * gv;
    out_c[off] = c;
    out_h[off] = ov * tanhf(c);
  }
}

// ===========================================================================
// Kernel 2: attention per (p, head) block, all 8 rollouts inside.
// K/V read ONCE per block.  Emits per-head partial of qm = x @ nn_O via
// atomicAdd into zero-initialized qm workspace.
// ===========================================================================
__global__ __launch_bounds__(256) void k_attn2(
    const float* __restrict__ Kt, const float* __restrict__ Vt,
    const float* __restrict__ nn_Q, const float* __restrict__ nn_O,
    const void* __restrict__ maskp,
    const float* __restrict__ out_h, float* __restrict__ qm)
{
  const int p = blockIdx.x >> 3;
  const int a = blockIdx.x & 7;
  const int t = threadIdx.x;
  const int wave = t >> 6, lane = t & 63;

  __shared__ float hs[NRR][HDIM];   // 8 KB
  __shared__ float Qs[NRR][HD];     // 1 KB
  __shared__ float Sb[NRR][NKK];    // 16 KB
  __shared__ float xs[NRR][HD];     // 1 KB
  __shared__ int   mask_any;

  const unsigned char* mb = (const unsigned char*)maskp;
  const int* mi = (const int*)maskp;

  if (t == 0) mask_any = 0;
  __syncthreads();
  {
    int any = 0;
    for (int j = t; j < 2048; j += 256) any |= mb[2 * j + 1];
    if (any) atomicOr(&mask_any, 1);
  }

  for (int idx = t; idx < NRR * HDIM; idx += 256)
    hs[idx >> 8][idx & 255] = out_h[(size_t)(p * NRR + (idx >> 8)) * HDIM + (idx & 255)];
  __syncthreads();
  const bool mbyte = (mask_any != 0);

  // ---- Q projection: thread -> (r, d) ----
  {
    const int r = t >> 5, d = t & 31;
    const float* nq = nn_Q + ((size_t)a * HDIM) * HD + d;
    float acc = 0.f;
#pragma unroll 4
    for (int h = 0; h < HDIM; ++h) acc += hs[r][h] * nq[(size_t)h * HD];
    Qs[r][d] = acc * 0.17677669529663687f;   // 1/sqrt(32)
  }
  __syncthreads();

  // ---- scores: thread <-> k, all 8 rollouts ----
  for (int k = t; k < NKK; k += 256) {
    float kf[HD];
    const float4* kr4 = reinterpret_cast<const float4*>(
        Kt + (((size_t)a * NPP + p) * NKK + k) * HD);
#pragma unroll
    for (int d4 = 0; d4 < HD / 4; ++d4) {
      const float4 u = kr4[d4];
      kf[4 * d4 + 0] = u.x; kf[4 * d4 + 1] = u.y;
      kf[4 * d4 + 2] = u.z; kf[4 * d4 + 3] = u.w;
    }
#pragma unroll
    for (int r = 0; r < NRR; ++r) {
      const size_t mrow = (size_t)(p * NRR + r) * NKK + k;
      const bool mk = mbyte ? (mb[mrow] != 0) : (mi[mrow] != 0);
      float s = 0.f;
#pragma unroll
      for (int d4 = 0; d4 < HD / 4; ++d4) {
        const float4 q = *reinterpret_cast<const float4*>(&Qs[r][4 * d4]);
        s += q.x * kf[4 * d4] + q.y * kf[4 * d4 + 1]
           + q.z * kf[4 * d4 + 2] + q.w * kf[4 * d4 + 3];
      }
      Sb[r][k] = mk ? -INFINITY : s;
    }
  }
  __syncthreads();

  // ---- softmax per rollout: wave w -> rows 2w, 2w+1 ----
  for (int rr = 0; rr < 2; ++rr) {
    const int r = wave * 2 + rr;
    float m = -INFINITY;
    for (int k = lane; k < NKK; k += 64) m = fmaxf(m, Sb[r][k]);
#pragma unroll
    for (int off = 32; off > 0; off >>= 1) m = fmaxf(m, __shfl_xor(m, off, 64));
    float ssum = 0.f;
    for (int k = lane; k < NKK; k += 64) {
      const float e = expf(Sb[r][k] - m);
      Sb[r][k] = e;
      ssum += e;
    }
#pragma unroll
    for (int off = 32; off > 0; off >>= 1) ssum += __shfl_xor(ssum, off, 64);
    const float inv = 1.f / ssum;
    for (int k = lane; k < NKK; k += 64) Sb[r][k] *= inv;
  }
  __syncthreads();

  // ---- PV: thread -> (r, d), k unrolled by 4 with float4 prob reads ----
  {
    const int r = t >> 5, d = t & 31;
    const float* vb = Vt + ((size_t)a * NPP + p) * NKK * HD + d;
    float acc = 0.f;
    int k = 0;
    for (; k + 4 <= NKK; k += 4) {
      const float4 s4 = *reinterpret_cast<const float4*>(&Sb[r][k]);
      acc += s4.x * vb[(size_t)(k + 0) * HD] + s4.y * vb[(size_t)(k + 1) * HD]
           + s4.z * vb[(size_t)(k + 2) * HD] + s4.w * vb[(size_t)(k + 3) * HD];
    }
    for (; k < NKK; ++k) acc += Sb[r][k] * vb[(size_t)k * HD];
    xs[r][d] = acc;
  }
  __syncthreads();

  // ---- partial qm: thread = output col j; qm[b,j] += sum_d xs[r,d]*O[a*32+d,j]
  {
    float accq[NRR];
#pragma unroll
    for (int r = 0; r < NRR; ++r) accq[r] = 0.f;
    for (int d = 0; d < HD; ++d) {
      const float w = nn_O[((size_t)(a * HD + d)) * HDIM + t];
#pragma unroll
      for (int r = 0; r < NRR; ++r) accq[r] += xs[r][d] * w;
    }
#pragma unroll
    for (int r = 0; r < NRR; ++r)
      atomicAdd(&qm[(size_t)(p * NRR + r) * HDIM + t], accq[r]);
  }
}

// ===========================================================================
// Kernel 3: additive logits.  Grid 64 x 32 (k-tiles of 16).  Block = 4 waves;
// each wave owns 4 k values; lane owns 4 h.  X read exactly once globally.
// Writes l = mask ? -inf : tanh(logit)*10  to ls workspace.
// ===========================================================================
__global__ __launch_bounds__(256) void k_logits2(
    const float* __restrict__ X, const float* __restrict__ varfeat,
    const float* __restrict__ nn_A, const float* __restrict__ nn_B,
    const float* __restrict__ nn_W, const float* __restrict__ qm,
    const void* __restrict__ maskp, float* __restrict__ ls)
{
  const int p  = blockIdx.x >> 5;
  const int kt = blockIdx.x & 31;
  const int t = threadIdx.x;
  const int wave = t >> 6, lane = t & 63;
  const int h0 = lane * 4;

  __shared__ float As[VDIM][260];   // nn_A [v][h], padded
  __shared__ float Ws[HDIM];
  __shared__ float qb[NRR][260];    // qm + nn_B, padded
  __shared__ int   mask_any;

  const unsigned char* mb = (const unsigned char*)maskp;
  const int* mi = (const int*)maskp;

  if (t == 0) mask_any = 0;
  __syncthreads();
  {
    int any = 0;
    for (int j = t; j < 2048; j += 256) any |= mb[2 * j + 1];
    if (any) atomicOr(&mask_any, 1);
  }

  for (int idx = t; idx < VDIM * HDIM; idx += 256)
    As[idx >> 8][idx & 255] = nn_A[idx];
  Ws[t] = nn_W[t];
  for (int idx = t; idx < NRR * HDIM; idx += 256) {
    const int r = idx >> 8, h = idx & 255;
    qb[r][h] = qm[(size_t)(p * NRR + r) * HDIM + h] + nn_B[h];
  }
  __syncthreads();
  const bool mbyte = (mask_any != 0);

  const float4 w4 = *reinterpret_cast<const float4*>(&Ws[h0]);

  for (int kk = 0; kk < 4; ++kk) {
    const int k = kt * 16 + wave * 4 + kk;
    if (k >= NKK) break;

    // base = X + varfeat . A   (lane's 4 h)
    const float4 x4 = *reinterpret_cast<const float4*>(
        X + ((size_t)p * NKK + k) * HDIM + h0);
    float base0 = x4.x, base1 = x4.y, base2 = x4.z, base3 = x4.w;
#pragma unroll
    for (int v = 0; v < VDIM; ++v) {
      const float vv = varfeat[((size_t)p * VDIM + v) * NKK + k];
      const float4 a4 = *reinterpret_cast<const float4*>(&As[v][h0]);
      base0 += vv * a4.x; base1 += vv * a4.y;
      base2 += vv * a4.z; base3 += vv * a4.w;
    }

#pragma unroll
    for (int r = 0; r < NRR; ++r) {
      const float4 q4 = *reinterpret_cast<const float4*>(&qb[r][h0]);
      float acc = tanhf(base0 + q4.x) * w4.x + tanhf(base1 + q4.y) * w4.y
                + tanhf(base2 + q4.z) * w4.z + tanhf(base3 + q4.w) * w4.w;
#pragma unroll
      for (int off = 32; off > 0; off >>= 1) acc += __shfl_xor(acc, off, 64);
      if (lane == r) {   // all lanes hold the sum after the butterfly
        const size_t mrow = (size_t)(p * NRR + r) * NKK + k;
        const bool mk = mbyte ? (mb[mrow] != 0) : (mi[mrow] != 0);
        ls[mrow] = mk ? -INFINITY : tanhf(acc) * 10.0f;
      }
    }
  }
}

// ===========================================================================
// Kernel 4: choose.  One wave per batch row.  chosen_p = -log(sum exp(l-max)).
// ===========================================================================
__global__ __launch_bounds__(64) void k_choose(
    const float* __restrict__ ls, float* __restrict__ out_p)
{
  const int b = blockIdx.x;
  const int lane = threadIdx.x;
  float m = -INFINITY;
  float lv[8];
  int n = 0;
  for (int k = lane; k < NKK; k += 64, ++n) {
    lv[n] = ls[(size_t)b * NKK + k];
    m = fmaxf(m, lv[n]);
  }
#pragma unroll
  for (int off = 32; off > 0; off >>= 1) m = fmaxf(m, __shfl_xor(m, off, 64));
  float s = 0.f;
  for (int i = 0; i < n; ++i) s += expf(lv[i] - m);
#pragma unroll
  for (int off = 32; off > 0; off >>= 1) s += __shfl_xor(s, off, 64);
  if (lane == 0) out_p[b] = -logf(s);
}

// ===========================================================================
// Fallback (ws too small): round-3 fused kernel — known-correct.
// ===========================================================================
__global__ __launch_bounds__(256) void k_fused(
    const float* __restrict__ X, const float* __restrict__ Kt,
    const float* __restrict__ Vt, const float* __restrict__ varfeat,
    const void* __restrict__ maskp,
    const float* __restrict__ nn_Q, const float* __restrict__ nn_O,
    const float* __restrict__ nn_A, const float* __restrict__ nn_B,
    const float* __restrict__ nn_W,
    const float* __restrict__ out_h, float* __restrict__ out_p)
{
  const int p = blockIdx.x >> 3;
  const int r = blockIdx.x & 7;
  const int t = threadIdx.x;
  const int wave = t >> 6, lane = t & 63;

  __shared__ float hs[HDIM];
  __shared__ float Qs[NHEAD][HD];
  __shared__ float Sb[NHEAD][NKK];
  __shared__ float xs[HDIM];
  __shared__ float qs[HDIM];
  __shared__ float As2[HDIM][VDIM];
  __shared__ float Ws[HDIM];
  __shared__ float lsb[NKK];
  __shared__ int   mask_any;

  const unsigned char* mb = (const unsigned char*)maskp;
  if (t == 0) mask_any = 0;
  __syncthreads();
  {
    int any = 0;
    for (int j = t; j < 2048; j += 256) any |= mb[2 * j + 1];
    if (any) atomicOr(&mask_any, 1);
  }
  for (int idx = t; idx < VDIM * HDIM; idx += 256)
    As2[idx & 255][idx >> 8] = nn_A[idx];
  Ws[t] = nn_W[t];
  hs[t] = out_h[(size_t)(p * NRR + r) * HDIM + t];
  __syncthreads();
  const bool mbyte = (mask_any != 0);
  const int* mi = (const int*)maskp;
  const size_t mrow = (size_t)(p * NRR + r) * NKK;
  {
    const int a = t >> 5, d = t & 31;
    const float* nq = nn_Q + (size_t)a * HDIM * HD + d;
    float acc = 0.f;
    for (int h = 0; h < HDIM; ++h) acc += hs[h] * nq[(size_t)h * HD];
    Qs[a][d] = acc * 0.17677669529663687f;
  }
  __syncthreads();
  for (int k = t; k < NKK; k += 256) {
    const bool mk = mbyte ? (mb[mrow + k] != 0) : (mi[mrow + k] != 0);
#pragma unroll
    for (int a = 0; a < NHEAD; ++a) {
      const float4* kr4 = reinterpret_cast<const float4*>(
          Kt + (((size_t)a * NPP + p) * NKK + k) * HD);
      float s = 0.f;
#pragma unroll
      for (int d4 = 0; d4 < HD / 4; ++d4) {
        const float4 u = kr4[d4];
        s += Qs[a][4 * d4] * u.x + Qs[a][4 * d4 + 1] * u.y
           + Qs[a][4 * d4 + 2] * u.z + Qs[a][4 * d4 + 3] * u.w;
      }
      Sb[a][k] = mk ? -INFINITY : s;
    }
  }
  __syncthreads();
  for (int aa = 0; aa < 2; ++aa) {
    const int a = wave * 2 + aa;
    float m = -INFINITY;
    for (int k = lane; k < NKK; k += 64) m = fmaxf(m, Sb[a][k]);
#pragma unroll
    for (int off = 32; off > 0; off >>= 1) m = fmaxf(m, __shfl_xor(m, off, 64));
    float ssum = 0.f;
    for (int k = lane; k < NKK; k += 64) {
      const float e = expf(Sb[a][k] - m);
      Sb[a][k] = e; ssum += e;
    }
#pragma unroll
    for (int off = 32; off > 0; off >>= 1) ssum += __shfl_xor(ssum, off, 64);
    const float inv = 1.f / ssum;
    for (int k = lane; k < NKK; k += 64) Sb[a][k] *= inv;
  }
  __syncthreads();
  {
    const int a = t >> 5, d = t & 31;
    const float* vb = Vt + ((size_t)a * NPP + p) * NKK * HD + d;
    float acc = 0.f;
    for (int k = 0; k < NKK; ++k) acc += Sb[a][k] * vb[(size_t)k * HD];
    xs[a * HD + d] = acc;
  }
  __syncthreads();
  {
    float acc = 0.f;
    for (int i = 0; i < HDIM; ++i) acc += xs[i] * nn_O[(size_t)i * HDIM + t];
    qs[t] = acc + nn_B[t];
  }
  __syncthreads();
  for (int k = t; k < NKK; k += 256) {
    float vfv[VDIM];
#pragma unroll
    for (int v = 0; v < VDIM; ++v)
      vfv[v] = varfeat[((size_t)p * VDIM + v) * NKK + k];
    const float4* xp4 = reinterpret_cast<const float4*>(
        X + ((size_t)p * NKK + k) * HDIM);
    float acc = 0.f;
    for (int h4 = 0; h4 < HDIM / 4; ++h4) {
      const float4 ux = xp4[h4];
      const float xv[4] = {ux.x, ux.y, ux.z, ux.w};
#pragma unroll
      for (int j = 0; j < 4; ++j) {
        const int h = 4 * h4 + j;
        float base = xv[j] + qs[h];
        const float4 a0 = *reinterpret_cast<const float4*>(&As2[h][0]);
        const float4 a1 = *reinterpret_cast<const float4*>(&As2[h][4]);
        base += vfv[0] * a0.x + vfv[1] * a0.y + vfv[2] * a0.z + vfv[3] * a0.w
              + vfv[4] * a1.x + vfv[5] * a1.y + vfv[6] * a1.z + vfv[7] * a1.w;
        acc += tanhf(base) * Ws[h];
      }
    }
    lsb[k] = acc;
  }
  __syncthreads();
  for (int k = t; k < NKK; k += 256) {
    const bool mk = mbyte ? (mb[mrow + k] != 0) : (mi[mrow + k] != 0);
    lsb[k] = mk ? -INFINITY : tanhf(lsb[k]) * 10.0f;
  }
  __syncthreads();
  if (wave == 0) {
    float m = -INFINITY;
    for (int k = lane; k < NKK; k += 64) m = fmaxf(m, lsb[k]);
#pragma unroll
    for (int off = 32; off > 0; off >>= 1) m = fmaxf(m, __shfl_xor(m, off, 64));
    float s = 0.f;
    for (int k = lane; k < NKK; k += 64) s += expf(lsb[k] - m);
#pragma unroll
    for (int off = 32; off > 0; off >>= 1) s += __shfl_xor(s, off, 64);
    if (lane == 0) out_p[p * NRR + r] = -logf(s);
  }
}

// ===========================================================================
extern "C" void kernel_launch(void* const* d_in, const int* in_sizes, int n_in,
                              void* d_out, int out_size, void* d_ws, size_t ws_size,
                              hipStream_t stream)
{
  const float* X       = (const float*)d_in[0];
  const float* Kt      = (const float*)d_in[1];
  const float* Vt      = (const float*)d_in[2];
  const float* query   = (const float*)d_in[3];
  const float* state1  = (const float*)d_in[4];
  const float* state2  = (const float*)d_in[5];
  const float* varfeat = (const float*)d_in[6];
  const void*  maskp   = d_in[7];
  const float* nn_Q    = (const float*)d_in[8];
  const float* nn_O    = (const float*)d_in[9];
  const float* nn_A    = (const float*)d_in[10];
  const float* nn_B    = (const float*)d_in[11];
  const float* nn_W    = (const float*)d_in[12];
  const float* W_ih    = (const float*)d_in[13];
  const float* W_hh    = (const float*)d_in[14];
  const float* b_ih    = (const float*)d_in[15];
  const float* b_hh    = (const float*)d_in[16];

  float* out   = (float*)d_out;
  float* out_h = out;                              // [512,256]
  float* out_c = out + (size_t)BTOT * HDIM;        // [512,256]
  float* out_p = out + (size_t)2 * BTOT * HDIM;    // [512]

  hipLaunchKernelGGL(k_lstm2, dim3(256), dim3(256), 0, stream,
                     query, state1, state2, W_ih, W_hh, b_ih, b_hh,
                     out_h, out_c);

  const size_t qm_bytes = (size_t)BTOT * HDIM * 4;           // 512 KB
  const size_t ls_bytes = (size_t)BTOT * NKK * 4;            // 1.0 MB
  if (ws_size >= qm_bytes + ls_bytes) {
    float* qm = (float*)d_ws;
    float* ls = (float*)((char*)d_ws + qm_bytes);
    hipMemsetAsync(qm, 0, qm_bytes, stream);
    hipLaunchKernelGGL(k_attn2, dim3(NPP * NHEAD), dim3(256), 0, stream,
                       Kt, Vt, nn_Q, nn_O, maskp, out_h, qm);
    hipLaunchKernelGGL(k_logits2, dim3(NPP * 32), dim3(256), 0, stream,
                       X, varfeat, nn_A, nn_B, nn_W, qm, maskp, ls);
    hipLaunchKernelGGL(k_choose, dim3(BTOT), dim3(64), 0, stream,
                       ls, out_p);
  } else {
    hipLaunchKernelGGL(k_fused, dim3(NPP * NRR), dim3(256), 0, stream,
                       X, Kt, Vt, varfeat, maskp,
                       nn_Q, nn_O, nn_A, nn_B, nn_W,
                       out_h, out_p);
  }
}

// Round 6
// 304.859 us; speedup vs baseline: 1.7915x; 1.0771x over previous
//
#include <hip/hip_runtime.h>

// Problem constants (from reference) — ALL TENSORS ARE FLOAT32.
#define NPP   64
#define NRR   8
#define NKK   500
#define HDIM  256
#define NHEAD 8
#define VDIM  8
#define HD    32
#define BTOT  512   // NPP*NRR

__device__ __forceinline__ float sigf(float x) { return 1.f / (1.f + expf(-x)); }

// ===========================================================================
// Kernel 1: LSTM cell, tiled GEMM, 32 gate-rows x 32 batch tiles.
// Grid 32 (h-tiles) x 16 (batch-tiles) = 512 blocks, 256 thr.
// ===========================================================================
__global__ __launch_bounds__(256) void k_lstm3(
    const float* __restrict__ query, const float* __restrict__ state1,
    const float* __restrict__ state2,
    const float* __restrict__ W_ih, const float* __restrict__ W_hh,
    const float* __restrict__ b_ih, const float* __restrict__ b_hh,
    float* __restrict__ out_h, float* __restrict__ out_c)
{
  __shared__ float Wt[32][33];   // [kk][row_local]
  __shared__ float At[32][33];   // [kk][batch_local]
  __shared__ float gt[32][33];   // [row_local][batch_local]

  const int t  = threadIdx.x;
  const int hb = blockIdx.x;     // 0..31 (8 h per part)
  const int bb = blockIdx.y;     // 0..15 (32 batch)

  const int trow = t >> 4;       // 0..15 -> rows trow, trow+16
  const int tcol = t & 15;       // 0..15 -> cols tcol, tcol+16

  float acc00 = 0.f, acc01 = 0.f, acc10 = 0.f, acc11 = 0.f;

  // W-load: wrow = t>>3 (0..31), wk4 = t&7 (float4)
  const int wrow = t >> 3, wk4 = t & 7;
  const int wpart = wrow >> 3, whh = wrow & 7;
  const int wgrow = wpart * HDIM + hb * 8 + whh;
  const int agrow = bb * 32 + wrow;

  for (int k0 = 0; k0 < 512; k0 += 32) {
    __syncthreads();
    {
      const float* wsrc = (k0 < 256) ? (W_ih + (size_t)wgrow * HDIM + k0)
                                     : (W_hh + (size_t)wgrow * HDIM + (k0 - 256));
      const float4 wv = *reinterpret_cast<const float4*>(wsrc + wk4 * 4);
      Wt[wk4 * 4 + 0][wrow] = wv.x; Wt[wk4 * 4 + 1][wrow] = wv.y;
      Wt[wk4 * 4 + 2][wrow] = wv.z; Wt[wk4 * 4 + 3][wrow] = wv.w;

      const float* asrc = (k0 < 256) ? (query  + (size_t)agrow * HDIM + k0)
                                     : (state1 + (size_t)agrow * HDIM + (k0 - 256));
      const float4 av = *reinterpret_cast<const float4*>(asrc + wk4 * 4);
      At[wk4 * 4 + 0][wrow] = av.x; At[wk4 * 4 + 1][wrow] = av.y;
      At[wk4 * 4 + 2][wrow] = av.z; At[wk4 * 4 + 3][wrow] = av.w;
    }
    __syncthreads();

#pragma unroll 8
    for (int kk = 0; kk < 32; ++kk) {
      const float w0 = Wt[kk][trow], w1 = Wt[kk][trow + 16];
      const float a0 = At[kk][tcol], a1 = At[kk][tcol + 16];
      acc00 += w0 * a0; acc01 += w0 * a1;
      acc10 += w1 * a0; acc11 += w1 * a1;
    }
  }

  gt[trow][tcol] = acc00;      gt[trow][tcol + 16] = acc01;
  gt[trow + 16][tcol] = acc10; gt[trow + 16][tcol + 16] = acc11;
  __syncthreads();

  // epilogue: thread -> (h = t&7, b = t>>3)
  {
    const int h = t & 7, b = t >> 3;
    const int gh = hb * 8 + h;
    const int gb = bb * 32 + b;
    const float bi = b_ih[0 * HDIM + gh] + b_hh[0 * HDIM + gh];
    const float bf = b_ih[1 * HDIM + gh] + b_hh[1 * HDIM + gh];
    const float bg = b_ih[2 * HDIM + gh] + b_hh[2 * HDIM + gh];
    const float bo = b_ih[3 * HDIM + gh] + b_hh[3 * HDIM + gh];
    const float iv = sigf (gt[ 0 + h][b] + bi);
    const float fv = sigf (gt[ 8 + h][b] + bf);
    const float gv = tanhf(gt[16 + h][b] + bg);
    const float ov = sigf (gt[24 + h][b] + bo);
    const size_t off = (size_t)gb * HDIM + gh;
    const float c = fv * state2[off] + iv * gv;
    out_c[off] = c;
    out_h[off] = ov * tanhf(c);
  }
}

// ===========================================================================
// Kernel 2: attention per (p, head).  LDS-staged nn_Q, k-split PV with 8
// independent chains.  Emits qm partial via atomicAdd (qm pre-zeroed).
// ===========================================================================
__global__ __launch_bounds__(256) void k_attn3(
    const float* __restrict__ Kt, const float* __restrict__ Vt,
    const float* __restrict__ nn_Q, const float* __restrict__ nn_O,
    const void* __restrict__ maskp,
    const float* __restrict__ out_h, float* __restrict__ qm)
{
  const int p = blockIdx.x >> 3;
  const int a = blockIdx.x & 7;
  const int t = threadIdx.x;
  const int wave = t >> 6, lane = t & 63;

  __shared__ float hs[NRR][HDIM];   // 8 KB
  __shared__ float Wst[64 * HD];    // 8 KB  (nn_Q chunk, [hh][d] d-fast)
  __shared__ float Qs[NRR][HD];     // 1 KB  (later reused for xs)
  __shared__ float Sb[NRR][NKK];    // 16 KB
  __shared__ float xp[8][NRR * HD]; // 8 KB  (PV partials per ksub)
  __shared__ int   mask_any;

  const unsigned char* mb = (const unsigned char*)maskp;
  const int* mi = (const int*)maskp;

  if (t == 0) mask_any = 0;
  __syncthreads();
  {
    int any = 0;
    for (int j = t; j < 2048; j += 256) any |= mb[2 * j + 1];
    if (any) atomicOr(&mask_any, 1);
  }

  for (int idx = t; idx < NRR * HDIM / 4; idx += 256) {
    const float4 v = reinterpret_cast<const float4*>(
        out_h + (size_t)p * NRR * HDIM)[idx];
    reinterpret_cast<float4*>(&hs[0][0])[idx] = v;
  }
  __syncthreads();
  const bool mbyte = (mask_any != 0);

  // ---- Q projection with LDS-staged weights: thread -> (r, d) ----
  {
    const int r = t >> 5, d = t & 31;
    float qacc = 0.f;
    for (int c = 0; c < 4; ++c) {
      __syncthreads();
      {
        const float4* src = reinterpret_cast<const float4*>(
            nn_Q + (size_t)a * HDIM * HD + c * 2048);
        const float4 v0 = src[t * 2], v1 = src[t * 2 + 1];
        reinterpret_cast<float4*>(Wst)[t * 2] = v0;
        reinterpret_cast<float4*>(Wst)[t * 2 + 1] = v1;
      }
      __syncthreads();
#pragma unroll 8
      for (int hh = 0; hh < 64; ++hh)
        qacc += hs[r][c * 64 + hh] * Wst[hh * HD + d];
    }
    Qs[r][d] = qacc * 0.17677669529663687f;   // 1/sqrt(32)
  }
  __syncthreads();

  // ---- scores: thread <-> k, all 8 rollouts ----
  for (int k = t; k < NKK; k += 256) {
    float kf[HD];
    const float4* kr4 = reinterpret_cast<const float4*>(
        Kt + (((size_t)a * NPP + p) * NKK + k) * HD);
#pragma unroll
    for (int d4 = 0; d4 < HD / 4; ++d4) {
      const float4 u = kr4[d4];
      kf[4 * d4 + 0] = u.x; kf[4 * d4 + 1] = u.y;
      kf[4 * d4 + 2] = u.z; kf[4 * d4 + 3] = u.w;
    }
#pragma unroll
    for (int r = 0; r < NRR; ++r) {
      const size_t mrow = (size_t)(p * NRR + r) * NKK + k;
      const bool mk = mbyte ? (mb[mrow] != 0) : (mi[mrow] != 0);
      float s = 0.f;
#pragma unroll
      for (int d4 = 0; d4 < HD / 4; ++d4) {
        const float4 q = *reinterpret_cast<const float4*>(&Qs[r][4 * d4]);
        s += q.x * kf[4 * d4] + q.y * kf[4 * d4 + 1]
           + q.z * kf[4 * d4 + 2] + q.w * kf[4 * d4 + 3];
      }
      Sb[r][k] = mk ? -INFINITY : s;
    }
  }
  __syncthreads();

  // ---- softmax per rollout: wave w -> rows 2w, 2w+1 ----
  for (int rr = 0; rr < 2; ++rr) {
    const int r = wave * 2 + rr;
    float m = -INFINITY;
    for (int k = lane; k < NKK; k += 64) m = fmaxf(m, Sb[r][k]);
#pragma unroll
    for (int off = 32; off > 0; off >>= 1) m = fmaxf(m, __shfl_xor(m, off, 64));
    float ssum = 0.f;
    for (int k = lane; k < NKK; k += 64) {
      const float e = expf(Sb[r][k] - m);
      Sb[r][k] = e;
      ssum += e;
    }
#pragma unroll
    for (int off = 32; off > 0; off >>= 1) ssum += __shfl_xor(ssum, off, 64);
    const float inv = 1.f / ssum;
    for (int k = lane; k < NKK; k += 64) Sb[r][k] *= inv;
  }
  __syncthreads();

  // ---- PV, k-split: thread -> (ksub = t>>5, d = t&31); 8 chains (one/r) ----
  {
    const int ksub = t >> 5, d = t & 31;
    float acc[NRR];
#pragma unroll
    for (int r = 0; r < NRR; ++r) acc[r] = 0.f;
    const float* vb = Vt + ((size_t)a * NPP + p) * NKK * HD + d;
    for (int k = ksub; k < NKK; k += 8) {
      const float v = vb[(size_t)k * HD];
#pragma unroll
      for (int r = 0; r < NRR; ++r) acc[r] += Sb[r][k] * v;
    }
#pragma unroll
    for (int r = 0; r < NRR; ++r) xp[ksub][r * HD + d] = acc[r];
  }
  __syncthreads();

  // ---- reduce ksub partials -> xs (reuse Qs) ----
  {
    const int r = t >> 5, d = t & 31;
    float s = 0.f;
#pragma unroll
    for (int ks = 0; ks < 8; ++ks) s += xp[ks][r * HD + d];
    Qs[r][d] = s;
  }
  __syncthreads();

  // ---- partial qm: thread = output col j ----
  {
    float accq[NRR];
#pragma unroll
    for (int r = 0; r < NRR; ++r) accq[r] = 0.f;
    for (int d = 0; d < HD; ++d) {
      const float w = nn_O[((size_t)(a * HD + d)) * HDIM + t];
#pragma unroll
      for (int r = 0; r < NRR; ++r) accq[r] += Qs[r][d] * w;
    }
#pragma unroll
    for (int r = 0; r < NRR; ++r)
      atomicAdd(&qm[(size_t)(p * NRR + r) * HDIM + t], accq[r]);
  }
}

// ===========================================================================
// Kernel 3: additive logits.  Grid 64 x 32.  Wave owns 4 k; lane owns 4 h.
// Multi-value split reduction (17 shuffles for all 8 rollouts).
// BOUNDS GUARD restored: k can reach 511 at kt=31 — must skip k >= 500
// (round-5 regression: OOB ls writes corrupted the next row's logits).
// ===========================================================================
__global__ __launch_bounds__(256) void k_logits3(
    const float* __restrict__ X, const float* __restrict__ varfeat,
    const float* __restrict__ nn_A, const float* __restrict__ nn_B,
    const float* __restrict__ nn_W, const float* __restrict__ qm,
    const void* __restrict__ maskp, float* __restrict__ ls)
{
  const int p  = blockIdx.x >> 5;
  const int kt = blockIdx.x & 31;
  const int t = threadIdx.x;
  const int wave = t >> 6, lane = t & 63;
  const int h0 = lane * 4;

  __shared__ float As[VDIM][260];
  __shared__ float Ws[HDIM];
  __shared__ float qb[NRR][260];
  __shared__ int   mask_any;

  const unsigned char* mb = (const unsigned char*)maskp;
  const int* mi = (const int*)maskp;

  if (t == 0) mask_any = 0;
  __syncthreads();
  {
    int any = 0;
    for (int j = t; j < 2048; j += 256) any |= mb[2 * j + 1];
    if (any) atomicOr(&mask_any, 1);
  }

  for (int idx = t; idx < VDIM * HDIM; idx += 256)
    As[idx >> 8][idx & 255] = nn_A[idx];
  Ws[t] = nn_W[t];
  for (int idx = t; idx < NRR * HDIM; idx += 256) {
    const int r = idx >> 8, h = idx & 255;
    qb[r][h] = qm[(size_t)(p * NRR + r) * HDIM + h] + nn_B[h];
  }
  __syncthreads();
  const bool mbyte = (mask_any != 0);

  const float4 w4 = *reinterpret_cast<const float4*>(&Ws[h0]);

  for (int kk = 0; kk < 4; ++kk) {
    const int k = kt * 16 + wave * 4 + kk;
    if (k >= NKK) break;   // wave-uniform: k depends only on (wave, kk)

    const float4 x4 = *reinterpret_cast<const float4*>(
        X + ((size_t)p * NKK + k) * HDIM + h0);
    float base0 = x4.x, base1 = x4.y, base2 = x4.z, base3 = x4.w;
#pragma unroll
    for (int v = 0; v < VDIM; ++v) {
      const float vv = varfeat[((size_t)p * VDIM + v) * NKK + k];
      const float4 a4 = *reinterpret_cast<const float4*>(&As[v][h0]);
      base0 += vv * a4.x; base1 += vv * a4.y;
      base2 += vv * a4.z; base3 += vv * a4.w;
    }

    float acc[NRR];
#pragma unroll
    for (int r = 0; r < NRR; ++r) {
      const float4 q4 = *reinterpret_cast<const float4*>(&qb[r][h0]);
      acc[r] = tanhf(base0 + q4.x) * w4.x + tanhf(base1 + q4.y) * w4.y
             + tanhf(base2 + q4.z) * w4.z + tanhf(base3 + q4.w) * w4.w;
    }

    // ---- multi-value wave reduction: 8 sums across 64 lanes ----
    float v4[4];
    {
      float sw[8];
#pragma unroll
      for (int j = 0; j < 8; ++j) sw[j] = __shfl_xor(acc[j], 32, 64);
      const bool hi = (lane & 32) != 0;
#pragma unroll
      for (int j = 0; j < 4; ++j)
        v4[j] = hi ? (acc[j + 4] + sw[j + 4]) : (acc[j] + sw[j]);
    }
    float v2[2];
    {
      float sw[4];
#pragma unroll
      for (int j = 0; j < 4; ++j) sw[j] = __shfl_xor(v4[j], 16, 64);
      const bool hi = (lane & 16) != 0;
      v2[0] = hi ? (v4[2] + sw[2]) : (v4[0] + sw[0]);
      v2[1] = hi ? (v4[3] + sw[3]) : (v4[1] + sw[1]);
    }
    float w;
    {
      const float s0 = __shfl_xor(v2[0], 8, 64);
      const float s1 = __shfl_xor(v2[1], 8, 64);
      w = ((lane & 8) != 0) ? (v2[1] + s1) : (v2[0] + s0);
    }
    w += __shfl_xor(w, 4, 64);
    w += __shfl_xor(w, 2, 64);
    w += __shfl_xor(w, 1, 64);

    if ((lane & 7) == 0) {
      const int r = lane >> 3;
      const size_t mrow = (size_t)(p * NRR + r) * NKK + k;
      const bool mk = mbyte ? (mb[mrow] != 0) : (mi[mrow] != 0);
      ls[mrow] = mk ? -INFINITY : tanhf(w) * 10.0f;
    }
  }
}

// ===========================================================================
// Kernel 4: choose.  One wave per batch row.  chosen_p = -log(sum exp(l-max)).
// ===========================================================================
__global__ __launch_bounds__(64) void k_choose(
    const float* __restrict__ ls, float* __restrict__ out_p)
{
  const int b = blockIdx.x;
  const int lane = threadIdx.x;
  float m = -INFINITY;
  float lv[8];
  int n = 0;
  for (int k = lane; k < NKK; k += 64, ++n) {
    lv[n] = ls[(size_t)b * NKK + k];
    m = fmaxf(m, lv[n]);
  }
#pragma unroll
  for (int off = 32; off > 0; off >>= 1) m = fmaxf(m, __shfl_xor(m, off, 64));
  float s = 0.f;
  for (int i = 0; i < n; ++i) s += expf(lv[i] - m);
#pragma unroll
  for (int off = 32; off > 0; off >>= 1) s += __shfl_xor(s, off, 64);
  if (lane == 0) out_p[b] = -logf(s);
}

// ===========================================================================
// Fallback (ws too small): round-3 fused kernel — known-correct.
// ===========================================================================
__global__ __launch_bounds__(256) void k_fused(
    const float* __restrict__ X, const float* __restrict__ Kt,
    const float* __restrict__ Vt, const float* __restrict__ varfeat,
    const void* __restrict__ maskp,
    const float* __restrict__ nn_Q, const float* __restrict__ nn_O,
    const float* __restrict__ nn_A, const float* __restrict__ nn_B,
    const float* __restrict__ nn_W,
    const float* __restrict__ out_h, float* __restrict__ out_p)
{
  const int p = blockIdx.x >> 3;
  const int r = blockIdx.x & 7;
  const int t = threadIdx.x;
  const int wave = t >> 6, lane = t & 63;

  __shared__ float hs[HDIM];
  __shared__ float Qs[NHEAD][HD];
  __shared__ float Sb[NHEAD][NKK];
  __shared__ float xs[HDIM];
  __shared__ float qs[HDIM];
  __shared__ float As2[HDIM][VDIM];
  __shared__ float Ws[HDIM];
  __shared__ float lsb[NKK];
  __shared__ int   mask_any;

  const unsigned char* mb = (const unsigned char*)maskp;
  if (t == 0) mask_any = 0;
  __syncthreads();
  {
    int any = 0;
    for (int j = t; j < 2048; j += 256) any |= mb[2 * j + 1];
    if (any) atomicOr(&mask_any, 1);
  }
  for (int idx = t; idx < VDIM * HDIM; idx += 256)
    As2[idx & 255][idx >> 8] = nn_A[idx];
  Ws[t] = nn_W[t];
  hs[t] = out_h[(size_t)(p * NRR + r) * HDIM + t];
  __syncthreads();
  const bool mbyte = (mask_any != 0);
  const int* mi = (const int*)maskp;
  const size_t mrow = (size_t)(p * NRR + r) * NKK;
  {
    const int a = t >> 5, d = t & 31;
    const float* nq = nn_Q + (size_t)a * HDIM * HD + d;
    float acc = 0.f;
    for (int h = 0; h < HDIM; ++h) acc += hs[h] * nq[(size_t)h * HD];
    Qs[a][d] = acc * 0.17677669529663687f;
  }
  __syncthreads();
  for (int k = t; k < NKK; k += 256) {
    const bool mk = mbyte ? (mb[mrow + k] != 0) : (mi[mrow + k] != 0);
#pragma unroll
    for (int a = 0; a < NHEAD; ++a) {
      const float4* kr4 = reinterpret_cast<const float4*>(
          Kt + (((size_t)a * NPP + p) * NKK + k) * HD);
      float s = 0.f;
#pragma unroll
      for (int d4 = 0; d4 < HD / 4; ++d4) {
        const float4 u = kr4[d4];
        s += Qs[a][4 * d4] * u.x + Qs[a][4 * d4 + 1] * u.y
           + Qs[a][4 * d4 + 2] * u.z + Qs[a][4 * d4 + 3] * u.w;
      }
      Sb[a][k] = mk ? -INFINITY : s;
    }
  }
  __syncthreads();
  for (int aa = 0; aa < 2; ++aa) {
    const int a = wave * 2 + aa;
    float m = -INFINITY;
    for (int k = lane; k < NKK; k += 64) m = fmaxf(m, Sb[a][k]);
#pragma unroll
    for (int off = 32; off > 0; off >>= 1) m = fmaxf(m, __shfl_xor(m, off, 64));
    float ssum = 0.f;
    for (int k = lane; k < NKK; k += 64) {
      const float e = expf(Sb[a][k] - m);
      Sb[a][k] = e; ssum += e;
    }
#pragma unroll
    for (int off = 32; off > 0; off >>= 1) ssum += __shfl_xor(ssum, off, 64);
    const float inv = 1.f / ssum;
    for (int k = lane; k < NKK; k += 64) Sb[a][k] *= inv;
  }
  __syncthreads();
  {
    const int a = t >> 5, d = t & 31;
    const float* vb = Vt + ((size_t)a * NPP + p) * NKK * HD + d;
    float acc = 0.f;
    for (int k = 0; k < NKK; ++k) acc += Sb[a][k] * vb[(size_t)k * HD];
    xs[a * HD + d] = acc;
  }
  __syncthreads();
  {
    float acc = 0.f;
    for (int i = 0; i < HDIM; ++i) acc += xs[i] * nn_O[(size_t)i * HDIM + t];
    qs[t] = acc + nn_B[t];
  }
  __syncthreads();
  for (int k = t; k < NKK; k += 256) {
    float vfv[VDIM];
#pragma unroll
    for (int v = 0; v < VDIM; ++v)
      vfv[v] = varfeat[((size_t)p * VDIM + v) * NKK + k];
    const float4* xp4 = reinterpret_cast<const float4*>(
        X + ((size_t)p * NKK + k) * HDIM);
    float acc = 0.f;
    for (int h4 = 0; h4 < HDIM / 4; ++h4) {
      const float4 ux = xp4[h4];
      const float xv[4] = {ux.x, ux.y, ux.z, ux.w};
#pragma unroll
      for (int j = 0; j < 4; ++j) {
        const int h = 4 * h4 + j;
        float base = xv[j] + qs[h];
        const float4 a0 = *reinterpret_cast<const float4*>(&As2[h][0]);
        const float4 a1 = *reinterpret_cast<const float4*>(&As2[h][4]);
        base += vfv[0] * a0.x + vfv[1] * a0.y + vfv[2] * a0.z + vfv[3] * a0.w
              + vfv[4] * a1.x + vfv[5] * a1.y + vfv[6] * a1.z + vfv[7] * a1.w;
        acc += tanhf(base) * Ws[h];
      }
    }
    lsb[k] = acc;
  }
  __syncthreads();
  for (int k = t; k < NKK; k += 256) {
    const bool mk = mbyte ? (mb[mrow + k] != 0) : (mi[mrow + k] != 0);
    lsb[k] = mk ? -INFINITY : tanhf(lsb[k]) * 10.0f;
  }
  __syncthreads();
  if (wave == 0) {
    float m = -INFINITY;
    for (int k = lane; k < NKK; k += 64) m = fmaxf(m, lsb[k]);
#pragma unroll
    for (int off = 32; off > 0; off >>= 1) m = fmaxf(m, __shfl_xor(m, off, 64));
    float s = 0.f;
    for (int k = lane; k < NKK; k += 64) s += expf(lsb[k] - m);
#pragma unroll
    for (int off = 32; off > 0; off >>= 1) s += __shfl_xor(s, off, 64);
    if (lane == 0) out_p[p * NRR + r] = -logf(s);
  }
}

// ===========================================================================
extern "C" void kernel_launch(void* const* d_in, const int* in_sizes, int n_in,
                              void* d_out, int out_size, void* d_ws, size_t ws_size,
                              hipStream_t stream)
{
  const float* X       = (const float*)d_in[0];
  const float* Kt      = (const float*)d_in[1];
  const float* Vt      = (const float*)d_in[2];
  const float* query   = (const float*)d_in[3];
  const float* state1  = (const float*)d_in[4];
  const float* state2  = (const float*)d_in[5];
  const float* varfeat = (const float*)d_in[6];
  const void*  maskp   = d_in[7];
  const float* nn_Q    = (const float*)d_in[8];
  const float* nn_O    = (const float*)d_in[9];
  const float* nn_A    = (const float*)d_in[10];
  const float* nn_B    = (const float*)d_in[11];
  const float* nn_W    = (const float*)d_in[12];
  const float* W_ih    = (const float*)d_in[13];
  const float* W_hh    = (const float*)d_in[14];
  const float* b_ih    = (const float*)d_in[15];
  const float* b_hh    = (const float*)d_in[16];

  float* out   = (float*)d_out;
  float* out_h = out;
  float* out_c = out + (size_t)BTOT * HDIM;
  float* out_p = out + (size_t)2 * BTOT * HDIM;

  hipLaunchKernelGGL(k_lstm3, dim3(32, 16), dim3(256), 0, stream,
                     query, state1, state2, W_ih, W_hh, b_ih, b_hh,
                     out_h, out_c);

  const size_t qm_bytes = (size_t)BTOT * HDIM * 4;           // 512 KB
  const size_t ls_bytes = (size_t)BTOT * NKK * 4;            // 1.0 MB
  if (ws_size >= qm_bytes + ls_bytes) {
    float* qmw = (float*)d_ws;
    float* lsw = (float*)((char*)d_ws + qm_bytes);
    hipMemsetAsync(qmw, 0, qm_bytes, stream);
    hipLaunchKernelGGL(k_attn3, dim3(NPP * NHEAD), dim3(256), 0, stream,
                       Kt, Vt, nn_Q, nn_O, maskp, out_h, qmw);
    hipLaunchKernelGGL(k_logits3, dim3(NPP * 32), dim3(256), 0, stream,
                       X, varfeat, nn_A, nn_B, nn_W, qmw, maskp, lsw);
    hipLaunchKernelGGL(k_choose, dim3(BTOT), dim3(64), 0, stream,
                       lsw, out_p);
  } else {
    hipLaunchKernelGGL(k_fused, dim3(NPP * NRR), dim3(256), 0, stream,
                       X, Kt, Vt, varfeat, maskp,
                       nn_Q, nn_O, nn_A, nn_B, nn_W,
                       out_h, out_p);
  }
}